// Round 7
// baseline (298.244 us; speedup 1.0000x reference)
//
#include <hip/hip_runtime.h>
#include <hip/hip_bf16.h>

// out[b,p,c] = sum_s x[b,s,c] * W[c,p,s] + bias[c,p]
// x: [64,720,321] f32, W: [321,720,720] f32, bias: [321,720] f32, out: [64,720,321] f32
// R7 = R6 (linear-burst GEMM) + vmcnt-overflow hardening: R6's prologue had exactly
//     64 VMEM in flight == past the 6-bit vmcnt ceiling (63). Now: issue 56 (B+A0),
//     drain vmcnt(0) once, then issue A1 -> max 56 outstanding, steady-state 16.
// Design: BN=16 => per-block B = W[c, p0:p0+16, :] = one contiguous 46KB region,
//     staged whole-K as a 48-DMA linear burst (dominant 666MB stream is memcpy-
//     shaped). A: BK=64 double-buffered vmcnt pipeline from xt (L3-resident).
//     LDS 64KB exact -> 2 blocks/CU, 1 wave/block, barrier-free.

#define SEQ   720
#define PRED  720
#define CH    321
#define BATCH 64
#define RTOT  (BATCH*SEQ)
#define BNL   16
#define NTL   45                /* 720/16 p-tiles */
#define BN    144               /* legacy fallback tiling */
#define NCHUNK 21
#define NGROUP (NCHUNK*5)

typedef __attribute__((ext_vector_type(8))) short short8;
typedef __attribute__((ext_vector_type(4))) float f32x4;
typedef __attribute__((ext_vector_type(4))) unsigned short us4;
typedef unsigned int u32;

__device__ __forceinline__ short bf16bits(float f) {
    return __builtin_bit_cast(short, __float2bfloat16(f));
}

// async global->LDS DMA, 16B/lane. LDS dest = wave-uniform base (+lane*16 by HW);
// global src is per-lane.
__device__ __forceinline__ void gload16(const void* g, void* l) {
    __builtin_amdgcn_global_load_lds((const __attribute__((address_space(1))) u32*)g,
                                     (__attribute__((address_space(3))) u32*)l, 16, 0, 0);
}

// ---------------- x transpose: [46080][321] f32 -> [321][46080] bf16 ----------------
__global__ __launch_bounds__(256) void xpose_kernel(const float* __restrict__ x,
                                                    unsigned short* __restrict__ xt) {
    __shared__ float tile[64][33];
    const int bid = blockIdx.x;
    const int rt = bid % (RTOT/64);
    const int ct = bid / (RTOT/64);
    const int r0 = rt*64, c0 = ct*32;
    const int t  = threadIdx.x;
    const int cl = t & 31, rl0 = t >> 5;
    const int cg = c0 + cl;
    if (cg < CH) {
#pragma unroll
        for (int j = 0; j < 8; ++j) {
            int rl = rl0 + j*8;
            tile[rl][cl] = x[(size_t)(r0+rl)*CH + cg];
        }
    }
    __syncthreads();
#pragma unroll
    for (int j = 0; j < 8; ++j) {
        int idx = t + j*256;
        int c_l = idx >> 6;
        int r_l = idx & 63;
        if (c0 + c_l < CH)
            xt[(size_t)(c0+c_l)*RTOT + r0 + r_l] = (unsigned short)bf16bits(tile[r_l][c_l]);
    }
}

// ---------------- linear-burst GEMM: 1 wave/block, BN=16, whole-K B in LDS ----------------
// LDS B: [16 rows][192 chunks of 16B] f32 (180 real + 12 pad chunks per row); phys
//        chunk (16a+b') of row r holds logical chunk (16a + (b'^r)) — involution,
//        conflict-free reads, staging stays a linear 1KB-per-DMA burst.
// LDS A: [2][64 rows][8 chunks] bf16, phys chunk q of row r holds logical q^(r&7).
// K: 11 full BK=64 steps + tail of 16 (kch>=2 zeroed via B-frag).
template<bool STAGED>
__global__ __launch_bounds__(64) void gemm_lin_kernel(
        const float* __restrict__ W, const float* __restrict__ bias,
        const unsigned short* __restrict__ xt, void* __restrict__ outp) {
    __shared__ __align__(16) float          Bl[BNL*768];   // 49152 B
    __shared__ __align__(16) unsigned short Al[2][64*64];  // 16384 B  (total 64KB)

    const int bid = blockIdx.x;
    const int c   = bid / NTL;
    const int pt  = bid % NTL;
    const int p0  = pt * BNL;
    const int lane = threadIdx.x & 63;
    const int row = lane & 15, kch = lane >> 4;

    const float* Wc          = W  + (size_t)c * ((size_t)PRED * SEQ);
    const unsigned short* Xc = xt + (size_t)c * RTOT;

    // ---- B stage: 48 DMAs, linear 46KB burst (16 rows x 2880B contiguous) ----
    auto stageB = [&]() {
#pragma unroll
        for (int r = 0; r < 16; ++r)
#pragma unroll
            for (int j = 0; j < 3; ++j) {
                const int a = 4*j + (lane >> 4);
                int lc = (a << 4) | ((lane & 15) ^ r);   // logical 16B chunk in row
                if (lc > 179) lc = 176;                  // pad region: clamp (never read)
                gload16(Wc + (size_t)(p0 + r)*SEQ + lc*4, &Bl[(r*192 + j*64)*4]);
            }
    };
    // ---- A stage: 8 DMAs, [64][64] bf16, q^(r&7) swizzle ----
    auto stageA = [&](int buf, int kk) {
#pragma unroll
        for (int i = 0; i < 8; ++i) {
            const int r = 8*i + (lane >> 3);
            int sc = (lane & 7) ^ (r & 7);
            if (kk == 11) sc &= 1;                       // tail: clamp into s<720
            gload16(Xc + (size_t)r*SEQ + kk*64 + sc*8, &Al[buf][i*512]);
        }
    };

    f32x4 acc[4] = {};

    auto compute = [&](int buf, int k, int s, bool ztail) {
        short8 Af[4];
#pragma unroll
        for (int mi = 0; mi < 4; ++mi) {
            const int r2 = mi*16 + row;
            const int qa = (s*4 + kch) ^ (r2 & 7);
            Af[mi] = *reinterpret_cast<const short8*>(&Al[buf][r2*64 + qa*8]);
        }
        short8 Bf;
        {
            const int lc0 = k*16 + s*8 + 2*kch;
            const int ph0 = (lc0 & ~15) | ((lc0 & 15) ^ row);
            const int ph1 = ((lc0+1) & ~15) | (((lc0+1) & 15) ^ row);
            f32x4 lo = *reinterpret_cast<const f32x4*>(&Bl[row*768 + ph0*4]);
            f32x4 hi = *reinterpret_cast<const f32x4*>(&Bl[row*768 + ph1*4]);
            short8 v;
#pragma unroll
            for (int j = 0; j < 4; ++j) { v[j] = bf16bits(lo[j]); v[4+j] = bf16bits(hi[j]); }
            Bf = v;
        }
        if (ztail && kch >= 2) { short8 z = {}; Bf = z; }  // zero invalid K cols
#pragma unroll
        for (int mi = 0; mi < 4; ++mi)
            acc[mi] = __builtin_amdgcn_mfma_f32_16x16x32_bf16(Af[mi], Bf, acc[mi], 0, 0, 0);
    };

    stageB();            // 48 outstanding
    stageA(0, 0);        // 56 outstanding (<= 63: inside 6-bit vmcnt range)
    asm volatile("s_waitcnt vmcnt(0)" ::: "memory");   // one-time drain: B + A0 ready
    __builtin_amdgcn_sched_barrier(0);
    stageA(1, 1);        // 8 in flight
    for (int k = 0; k < 11; ++k) {
        const int buf = k & 1;
        if (k > 0) {
            // A(k) arrived; A(k+1)'s 8 DMAs stay in flight
            asm volatile("s_waitcnt vmcnt(8)" ::: "memory");
            __builtin_amdgcn_sched_barrier(0);
        }
        compute(buf, k, 0, false);
        compute(buf, k, 1, false);
        asm volatile("s_waitcnt lgkmcnt(0)" ::: "memory");   // my reads of A[buf] done
        __builtin_amdgcn_sched_barrier(0);
        if (k <= 9) stageA(buf, k + 2);    // refill just-freed buffer (16 in flight)
    }
    {   // k=11 tail (cols 704..719), buf 1
        asm volatile("s_waitcnt vmcnt(0)" ::: "memory");
        __builtin_amdgcn_sched_barrier(0);
        compute(1, 11, 0, true);
    }

    // Epilogue. C/D map: col = lane&15, row = (lane>>4)*4 + reg.
    const int col   = lane & 15;
    const int rquad = lane >> 4;
    const int p     = p0 + col;
    const float bv  = bias[(size_t)c*PRED + p];
    if (STAGED) {
        unsigned short* stg = (unsigned short*)outp;  // stage[c][p][b] bf16
#pragma unroll
        for (int mi = 0; mi < 4; ++mi) {
            us4 u;
#pragma unroll
            for (int r = 0; r < 4; ++r)
                u[r] = (unsigned short)bf16bits(acc[mi][r] + bv);
            *reinterpret_cast<us4*>(
                stg + ((size_t)c*PRED + p)*BATCH + mi*16 + rquad*4) = u;
        }
    } else {
        float* outf = (float*)outp;
#pragma unroll
        for (int mi = 0; mi < 4; ++mi)
#pragma unroll
            for (int r = 0; r < 4; ++r) {
                const int b = mi*16 + rquad*4 + r;
                outf[((size_t)b*PRED + p)*CH + c] = acc[mi][r] + bv;
            }
    }
}

// ---------------- fallback (no workspace): gather x directly, scattered stores ----------------
__global__ __launch_bounds__(192) void gemm_fallback_kernel(
        const float* __restrict__ W, const float* __restrict__ bias,
        const float* __restrict__ x, float* __restrict__ outp) {
    const int bid  = blockIdx.x;
    const int g    = (bid & 7) + 8*((bid >> 3) >> 4);
    const int coff = (bid >> 3) & 15;
    if (g >= NGROUP) return;
    const int c  = (g % NCHUNK)*16 + coff;
    if (c >= CH) return;
    const int p0 = (g / NCHUNK) * BN;
    const int tid = threadIdx.x, wv = tid >> 6, lane = tid & 63;
    const int row = lane & 15, kch = lane >> 4, nb = p0 + wv*48;
    const float* Wc = W + (size_t)c * ((size_t)PRED * SEQ);
    f32x4 acc[4][3] = {};
    for (int k = 0; k < 23; ++k) {
        const int kc = (k == 22) ? (kch & 1) : kch;
        const int s  = k*32 + kc*8;
        short8 Af[4], Bf[3];
#pragma unroll
        for (int mi = 0; mi < 4; ++mi) {
            short8 v;
#pragma unroll
            for (int j = 0; j < 8; ++j)
                v[j] = bf16bits(x[((size_t)(mi*16 + row)*SEQ + s + j)*CH + c]);
            Af[mi] = v;
        }
#pragma unroll
        for (int ni = 0; ni < 3; ++ni) {
            const float* p = Wc + (size_t)(nb + ni*16 + row)*SEQ + s;
            short8 v;
#pragma unroll
            for (int j = 0; j < 4; ++j) { v[j] = bf16bits(p[j]); v[4+j] = bf16bits(p[4+j]); }
            Bf[ni] = v;
        }
        if (k == 22 && kch >= 2) { short8 z = {}; Bf[0] = z; Bf[1] = z; Bf[2] = z; }
#pragma unroll
        for (int mi = 0; mi < 4; ++mi)
#pragma unroll
            for (int ni = 0; ni < 3; ++ni)
                acc[mi][ni] = __builtin_amdgcn_mfma_f32_16x16x32_bf16(
                                  Af[mi], Bf[ni], acc[mi][ni], 0, 0, 0);
    }
    const int col = lane & 15, rquad = lane >> 4;
#pragma unroll
    for (int ni = 0; ni < 3; ++ni) {
        const int p = nb + ni*16 + col;
        const float bv = bias[(size_t)c*PRED + p];
#pragma unroll
        for (int mi = 0; mi < 4; ++mi)
#pragma unroll
            for (int r = 0; r < 4; ++r)
                outp[((size_t)(mi*16 + rquad*4 + r)*PRED + p)*CH + c] = acc[mi][ni][r] + bv;
    }
}

// ---------------- unstage: stage[C][P][B] bf16 -> out[B][P][C] f32 ----------------
__global__ __launch_bounds__(256) void unstage_kernel(const unsigned short* __restrict__ stage,
                                                      float* __restrict__ out) {
    const int p  = blockIdx.x;
    const int c0 = blockIdx.y * 128;
    const int cn = (CH - c0 < 128) ? (CH - c0) : 128;
    __shared__ float tl[128][65];
    const int t = threadIdx.x;
    {
        const int b   = t & 63;
        const int ci0 = t >> 6;
        for (int ci = ci0; ci < cn; ci += 4) {
            unsigned short us = stage[((size_t)(c0+ci)*PRED + p)*BATCH + b];
            tl[ci][b] = __builtin_bit_cast(float, (u32)us << 16);
        }
    }
    __syncthreads();
    {
        const int cl = t & 127;
        const int b0 = t >> 7;
        if (cl < cn)
#pragma unroll
            for (int bb = b0; bb < BATCH; bb += 2)
                out[((size_t)bb*PRED + p)*CH + c0 + cl] = tl[cl][bb];
    }
}

extern "C" void kernel_launch(void* const* d_in, const int* in_sizes, int n_in,
                              void* d_out, int out_size, void* d_ws, size_t ws_size,
                              hipStream_t stream) {
    const float* x    = (const float*)d_in[0];
    const float* W    = (const float*)d_in[1];
    const float* bias = (const float*)d_in[2];
    float* out        = (float*)d_out;

    const size_t xt_bytes    = (size_t)CH * RTOT * sizeof(unsigned short);        // 29.6 MB
    const size_t stage_bytes = (size_t)CH * PRED * BATCH * sizeof(unsigned short);// 29.6 MB

    if (ws_size >= xt_bytes + stage_bytes) {
        unsigned short* xtp = (unsigned short*)d_ws;
        unsigned short* stg = (unsigned short*)((char*)d_ws + xt_bytes);
        xpose_kernel<<<dim3((RTOT/64) * 11), dim3(256), 0, stream>>>(x, xtp);
        gemm_lin_kernel<true><<<dim3(CH * NTL), dim3(64), 0, stream>>>(W, bias, xtp, stg);
        unstage_kernel<<<dim3(PRED, 3), dim3(256), 0, stream>>>(stg, out);
    } else if (ws_size >= xt_bytes) {
        unsigned short* xtp = (unsigned short*)d_ws;
        xpose_kernel<<<dim3((RTOT/64) * 11), dim3(256), 0, stream>>>(x, xtp);
        gemm_lin_kernel<false><<<dim3(CH * NTL), dim3(64), 0, stream>>>(W, bias, xtp, out);
    } else {
        gemm_fallback_kernel<<<dim3(8 * 14 * 16), dim3(192), 0, stream>>>(
            W, bias, x, out);
    }
}

// Round 9
// 242.895 us; speedup vs baseline: 1.2279x; 1.2279x over previous
//
#include <hip/hip_runtime.h>
#include <hip/hip_bf16.h>

// out[b,p,c] = sum_s x[b,s,c] * W[c,p,s] + bias[c,p]
// x: [64,720,321] f32, W: [321,720,720] f32, bias: [321,720] f32, out: [64,720,321] f32
// R9 = R8 (register-path W stream) with the asm crash fixed:
//   - B loads: one global_load_dwordx4 per asm statement, "=&v" EARLY-CLOBBER
//     (R8's "=v" let outputs alias the address inputs of async loads -> wild addr).
//   - values consumed only through tied s_waitcnt vmcnt(N) ("+v") + sched_barrier.
//   - __launch_bounds__(64,3): ~145 live VGPRs, no spill; 12 waves/CU.
//   - XCD-grouped grid: a channel's 15 p-tiles share bid%8 -> one L2 serves the
//     15x re-read of its 92KB xt slice.
// A stays on global_load_lds DMA (4KB/step dbuf, 8KB LDS total).

#define SEQ   720
#define PRED  720
#define CH    321
#define BATCH 64
#define RTOT  (BATCH*SEQ)
#define BN1   48
#define NT1   15                /* 720/48 p-tiles */
#define CPG   120               /* blocks per channel-group: 8 channels x 15 pt */
#define NBLKG 41                /* ceil(321/8) channel groups */
#define BN    144               /* legacy fallback tiling */
#define NCHUNK 21
#define NGROUP (NCHUNK*5)

typedef __attribute__((ext_vector_type(8))) short short8;
typedef __attribute__((ext_vector_type(4))) float f32x4;
typedef __attribute__((ext_vector_type(4))) unsigned short us4;
typedef unsigned int u32;

__device__ __forceinline__ short bf16bits(float f) {
    return __builtin_bit_cast(short, __float2bfloat16(f));
}

// async global->LDS DMA, 16B/lane. LDS dest = wave-uniform base (+lane*16 by HW).
__device__ __forceinline__ void gload16(const void* g, void* l) {
    __builtin_amdgcn_global_load_lds((const __attribute__((address_space(1))) u32*)g,
                                     (__attribute__((address_space(3))) u32*)l, 16, 0, 0);
}

// ---------------- x transpose: [46080][321] f32 -> [321][46080] bf16 ----------------
__global__ __launch_bounds__(256) void xpose_kernel(const float* __restrict__ x,
                                                    unsigned short* __restrict__ xt) {
    __shared__ float tile[64][33];
    const int bid = blockIdx.x;
    const int rt = bid % (RTOT/64);
    const int ct = bid / (RTOT/64);
    const int r0 = rt*64, c0 = ct*32;
    const int t  = threadIdx.x;
    const int cl = t & 31, rl0 = t >> 5;
    const int cg = c0 + cl;
    if (cg < CH) {
#pragma unroll
        for (int j = 0; j < 8; ++j) {
            int rl = rl0 + j*8;
            tile[rl][cl] = x[(size_t)(r0+rl)*CH + cg];
        }
    }
    __syncthreads();
#pragma unroll
    for (int j = 0; j < 8; ++j) {
        int idx = t + j*256;
        int c_l = idx >> 6;
        int r_l = idx & 63;
        if (c0 + c_l < CH)
            xt[(size_t)(c0+c_l)*RTOT + r0 + r_l] = (unsigned short)bf16bits(tile[r_l][c_l]);
    }
}

// ---------------- reg-path GEMM: 1 wave/block, BN=48, BK=32, asm B loads ----------------
template<bool STAGED>
__global__ __launch_bounds__(64, 3) void gemm_reg_kernel(
        const float* __restrict__ W, const float* __restrict__ bias,
        const unsigned short* __restrict__ xt, void* __restrict__ outp) {
    __shared__ __align__(16) unsigned short Al[2][64*32];   // 2 x 4 KB

    const int bid = blockIdx.x;
    const int c   = (bid / CPG) * 8 + (bid & 7);   // channel group -> same XCD slot
    const int pt  = (bid % CPG) >> 3;
    if (c >= CH) return;
    const int p0  = pt * BN1;
    const int lane = threadIdx.x & 63;
    const int row = lane & 15, kch = lane >> 4;

    const float* Wc          = W  + (size_t)c * ((size_t)PRED * SEQ);
    const unsigned short* Xc = xt + (size_t)c * RTOT;

    // per-lane 32-bit byte voffsets for the 3 B rows; step k adds k*128
    u32 vb[3], vbt[3];
#pragma unroll
    for (int ni = 0; ni < 3; ++ni) {
        vb[ni]  = (u32)(((p0 + ni*16 + row) * SEQ) * 4 + kch*32);
        vbt[ni] = (u32)(((p0 + ni*16 + row) * SEQ) * 4 + (kch & 1)*32);  // tail-clamped
    }

    // ---- A stage: 4 DMAs, [64][32] bf16, phys chunk q of row r = logical q^(r&3) ----
    auto stageA = [&](int buf, int kk) {
#pragma unroll
        for (int i = 0; i < 4; ++i) {
            const int r  = i*16 + (lane >> 2);
            int sc = (lane & 3) ^ (r & 3);
            if (kk == 22) sc &= 1;                    // tail: clamp into s<720
            gload16(Xc + (size_t)r*SEQ + kk*32 + sc*8, &Al[buf][i*512]);
        }
    };
    // ---- B stage: 6 asm loads (one per statement, EARLY-CLOBBER dest) ----
#define LOADB(B, KK, TAILC)                                                     \
    {                                                                           \
        _Pragma("unroll")                                                       \
        for (int ni = 0; ni < 3; ++ni) {                                        \
            u32 off = ((TAILC) ? vbt[ni] : vb[ni]) + (u32)(KK)*128u;            \
            asm volatile("global_load_dwordx4 %0, %1, %2"                       \
                         : "=&v"(B[2*ni])                                       \
                         : "v"(off), "s"(Wc) : "memory");                       \
            asm volatile("global_load_dwordx4 %0, %1, %2 offset:16"             \
                         : "=&v"(B[2*ni+1])                                     \
                         : "v"(off), "s"(Wc) : "memory");                       \
        }                                                                       \
    }
    // tied counted wait: B regs (and all older A DMAs) resident after this
#define WAITB(B, N)                                                             \
    asm volatile("s_waitcnt vmcnt(" #N ")"                                      \
                 : "+v"(B[0]), "+v"(B[1]), "+v"(B[2]),                          \
                   "+v"(B[3]), "+v"(B[4]), "+v"(B[5])                           \
                 :: "memory");                                                  \
    __builtin_amdgcn_sched_barrier(0);
#define LGKM0                                                                   \
    asm volatile("s_waitcnt lgkmcnt(0)" ::: "memory");                          \
    __builtin_amdgcn_sched_barrier(0);

    f32x4 acc[4][3] = {};
    f32x4 B0[6], B1[6];

    auto compute = [&](const unsigned short* Ab, f32x4 (&B)[6], bool ztail) {
        short8 Af[4];
#pragma unroll
        for (int mi = 0; mi < 4; ++mi) {
            const int r2 = mi*16 + row;
            const int qa = kch ^ (r2 & 3);
            Af[mi] = *reinterpret_cast<const short8*>(&Ab[r2*32 + qa*8]);
        }
        short8 Bf[3];
#pragma unroll
        for (int ni = 0; ni < 3; ++ni) {
            short8 v;
#pragma unroll
            for (int j = 0; j < 4; ++j) {
                v[j]   = bf16bits(B[2*ni][j]);
                v[4+j] = bf16bits(B[2*ni+1][j]);
            }
            Bf[ni] = v;
        }
        if (ztail && kch >= 2) { short8 z = {}; Bf[0] = z; Bf[1] = z; Bf[2] = z; }
#pragma unroll
        for (int mi = 0; mi < 4; ++mi)
#pragma unroll
            for (int ni = 0; ni < 3; ++ni)
                acc[mi][ni] = __builtin_amdgcn_mfma_f32_16x16x32_bf16(
                                  Af[mi], Bf[ni], acc[mi][ni], 0, 0, 0);
    };

    // prologue: stage(0), stage(1) -> 20 VMEM outstanding (< 63 vmcnt ceiling)
    stageA(0, 0); LOADB(B0, 0, false);
    stageA(1, 1); LOADB(B1, 1, false);

    for (int kk = 0; kk < 22; kk += 2) {
        WAITB(B0, 10);                         // stage(kk) done; stage(kk+1) in flight
        compute(&Al[0][0], B0, false);
        LGKM0;                                 // my ds_reads of Al[0] complete
        if (kk < 20) { stageA(0, kk + 2); LOADB(B0, kk + 2, false); }
        else         { stageA(0, 22);     LOADB(B0, 22,     true ); }  // tail stage
        __builtin_amdgcn_sched_barrier(0);

        WAITB(B1, 10);                         // stage(kk+1) done; next in flight
        compute(&Al[1][0], B1, false);
        LGKM0;
        if (kk < 20) { stageA(1, kk + 3); LOADB(B1, kk + 3, false); }
        __builtin_amdgcn_sched_barrier(0);
    }
    {   // k=22 tail (cols 704..719), in buf0
        WAITB(B0, 0);
        compute(&Al[0][0], B0, true);
    }

    // Epilogue. C/D map: col = lane&15, row = (lane>>4)*4 + reg.
    const int col   = lane & 15;
    const int rquad = lane >> 4;
    if (STAGED) {
        unsigned short* stg = (unsigned short*)outp;  // stage[c][p][b] bf16
#pragma unroll
        for (int ni = 0; ni < 3; ++ni) {
            const int p = p0 + ni*16 + col;
            const float bv = bias[(size_t)c*PRED + p];
#pragma unroll
            for (int mi = 0; mi < 4; ++mi) {
                us4 u;
#pragma unroll
                for (int r = 0; r < 4; ++r)
                    u[r] = (unsigned short)bf16bits(acc[mi][ni][r] + bv);
                *reinterpret_cast<us4*>(
                    stg + ((size_t)c*PRED + p)*BATCH + mi*16 + rquad*4) = u;
            }
        }
    } else {
        float* outf = (float*)outp;
#pragma unroll
        for (int ni = 0; ni < 3; ++ni) {
            const int p = p0 + ni*16 + col;
            const float bv = bias[(size_t)c*PRED + p];
#pragma unroll
            for (int mi = 0; mi < 4; ++mi)
#pragma unroll
                for (int r = 0; r < 4; ++r) {
                    const int b = mi*16 + rquad*4 + r;
                    outf[((size_t)b*PRED + p)*CH + c] = acc[mi][ni][r] + bv;
                }
        }
    }
#undef LOADB
#undef WAITB
#undef LGKM0
}

// ---------------- fallback (no workspace): gather x directly, scattered stores ----------------
__global__ __launch_bounds__(192) void gemm_fallback_kernel(
        const float* __restrict__ W, const float* __restrict__ bias,
        const float* __restrict__ x, float* __restrict__ outp) {
    const int bid  = blockIdx.x;
    const int g    = (bid & 7) + 8*((bid >> 3) >> 4);
    const int coff = (bid >> 3) & 15;
    if (g >= NGROUP) return;
    const int c  = (g % NCHUNK)*16 + coff;
    if (c >= CH) return;
    const int p0 = (g / NCHUNK) * BN;
    const int tid = threadIdx.x, wv = tid >> 6, lane = tid & 63;
    const int row = lane & 15, kch = lane >> 4, nb = p0 + wv*48;
    const float* Wc = W + (size_t)c * ((size_t)PRED * SEQ);
    f32x4 acc[4][3] = {};
    for (int k = 0; k < 23; ++k) {
        const int kc = (k == 22) ? (kch & 1) : kch;
        const int s  = k*32 + kc*8;
        short8 Af[4], Bf[3];
#pragma unroll
        for (int mi = 0; mi < 4; ++mi) {
            short8 v;
#pragma unroll
            for (int j = 0; j < 8; ++j)
                v[j] = bf16bits(x[((size_t)(mi*16 + row)*SEQ + s + j)*CH + c]);
            Af[mi] = v;
        }
#pragma unroll
        for (int ni = 0; ni < 3; ++ni) {
            const float* p = Wc + (size_t)(nb + ni*16 + row)*SEQ + s;
            short8 v;
#pragma unroll
            for (int j = 0; j < 4; ++j) { v[j] = bf16bits(p[j]); v[4+j] = bf16bits(p[4+j]); }
            Bf[ni] = v;
        }
        if (k == 22 && kch >= 2) { short8 z = {}; Bf[0] = z; Bf[1] = z; Bf[2] = z; }
#pragma unroll
        for (int mi = 0; mi < 4; ++mi)
#pragma unroll
            for (int ni = 0; ni < 3; ++ni)
                acc[mi][ni] = __builtin_amdgcn_mfma_f32_16x16x32_bf16(
                                  Af[mi], Bf[ni], acc[mi][ni], 0, 0, 0);
    }
    const int col = lane & 15, rquad = lane >> 4;
#pragma unroll
    for (int ni = 0; ni < 3; ++ni) {
        const int p = nb + ni*16 + col;
        const float bv = bias[(size_t)c*PRED + p];
#pragma unroll
        for (int mi = 0; mi < 4; ++mi)
#pragma unroll
            for (int r = 0; r < 4; ++r)
                outp[((size_t)(mi*16 + rquad*4 + r)*PRED + p)*CH + c] = acc[mi][ni][r] + bv;
    }
}

// ---------------- unstage: stage[C][P][B] bf16 -> out[B][P][C] f32 ----------------
__global__ __launch_bounds__(256) void unstage_kernel(const unsigned short* __restrict__ stage,
                                                      float* __restrict__ out) {
    const int p  = blockIdx.x;
    const int c0 = blockIdx.y * 128;
    const int cn = (CH - c0 < 128) ? (CH - c0) : 128;
    __shared__ float tl[128][65];
    const int t = threadIdx.x;
    {
        const int b   = t & 63;
        const int ci0 = t >> 6;
        for (int ci = ci0; ci < cn; ci += 4) {
            unsigned short us = stage[((size_t)(c0+ci)*PRED + p)*BATCH + b];
            tl[ci][b] = __builtin_bit_cast(float, (u32)us << 16);
        }
    }
    __syncthreads();
    {
        const int cl = t & 127;
        const int b0 = t >> 7;
        if (cl < cn)
#pragma unroll
            for (int bb = b0; bb < BATCH; bb += 2)
                out[((size_t)bb*PRED + p)*CH + c0 + cl] = tl[cl][bb];
    }
}

extern "C" void kernel_launch(void* const* d_in, const int* in_sizes, int n_in,
                              void* d_out, int out_size, void* d_ws, size_t ws_size,
                              hipStream_t stream) {
    const float* x    = (const float*)d_in[0];
    const float* W    = (const float*)d_in[1];
    const float* bias = (const float*)d_in[2];
    float* out        = (float*)d_out;

    const size_t xt_bytes    = (size_t)CH * RTOT * sizeof(unsigned short);        // 29.6 MB
    const size_t stage_bytes = (size_t)CH * PRED * BATCH * sizeof(unsigned short);// 29.6 MB

    if (ws_size >= xt_bytes + stage_bytes) {
        unsigned short* xtp = (unsigned short*)d_ws;
        unsigned short* stg = (unsigned short*)((char*)d_ws + xt_bytes);
        xpose_kernel<<<dim3((RTOT/64) * 11), dim3(256), 0, stream>>>(x, xtp);
        gemm_reg_kernel<true><<<dim3(NBLKG * CPG), dim3(64), 0, stream>>>(W, bias, xtp, stg);
        unstage_kernel<<<dim3(PRED, 3), dim3(256), 0, stream>>>(stg, out);
    } else if (ws_size >= xt_bytes) {
        unsigned short* xtp = (unsigned short*)d_ws;
        xpose_kernel<<<dim3((RTOT/64) * 11), dim3(256), 0, stream>>>(x, xtp);
        gemm_reg_kernel<false><<<dim3(NBLKG * CPG), dim3(64), 0, stream>>>(W, bias, xtp, out);
    } else {
        gemm_fallback_kernel<<<dim3(8 * 14 * 16), dim3(192), 0, stream>>>(
            W, bias, x, out);
    }
}